// Round 4
// baseline (704.835 us; speedup 1.0000x reference)
//
#include <hip/hip_runtime.h>
#include <hip/hip_cooperative_groups.h>

namespace cg = cooperative_groups;

#define NN 50000
#define EE 800000
#define RR 8
#define DD 128
#define SS (NN*RR)      // 400000 segments
#define TE (2*EE)       // 1600000 symmetrized edges
#define CSR_BLOCKS 512
#define CSR_GT (CSR_BLOCKS*256)   // 131072 threads

typedef __attribute__((ext_vector_type(8))) short bf16x8;
typedef __attribute__((ext_vector_type(4))) float f32x4;

__device__ __forceinline__ unsigned short f2bf(float f){
  unsigned int u = __float_as_uint(f);
  u += 0x7fffu + ((u >> 16) & 1u);   // round-to-nearest-even
  return (unsigned short)(u >> 16);
}
__device__ __forceinline__ float bf_lo(unsigned int w){ return __uint_as_float(w << 16); }
__device__ __forceinline__ float bf_hi(unsigned int w){ return __uint_as_float(w & 0xffff0000u); }

__device__ __forceinline__ void acc8(float* a, uint4 u){
  a[0] += bf_lo(u.x); a[1] += bf_hi(u.x);
  a[2] += bf_lo(u.y); a[3] += bf_hi(u.y);
  a[4] += bf_lo(u.z); a[5] += bf_hi(u.z);
  a[6] += bf_lo(u.w); a[7] += bf_hi(u.w);
}
__device__ __forceinline__ unsigned int pack2(float a, float b){
  return ((unsigned int)f2bf(b) << 16) | (unsigned int)f2bf(a);
}

// ---- single cooperative kernel: conv + CSR build --------------------------
// Phases: 0) zero counts, x->bf16, W->bf16^T   1) count  2) scan  3) scatter
__global__ __launch_bounds__(256) void k_csr(
    const float* __restrict__ x, const float* __restrict__ w,
    const float* __restrict__ sw, const int* __restrict__ ei,
    const int* __restrict__ et,
    unsigned short* __restrict__ xb, unsigned short* __restrict__ wb,
    int* __restrict__ counts, int* __restrict__ offs,
    int* __restrict__ cursor, int* __restrict__ esrc,
    int* __restrict__ blksum)
{
  cg::grid_group grid = cg::this_grid();
  const int tid  = threadIdx.x;
  const int bid  = blockIdx.x;
  const int gtid = bid*256 + tid;
  __shared__ int sd[256];

  // ---- phase 0: zero counts + conv_x + conv_w ----
  for (int i = gtid; i < SS; i += CSR_GT) counts[i] = 0;
  for (int i = gtid; i < NN*DD/4; i += CSR_GT){
    float4 v = ((const float4*)x)[i];
    ushort4 o;
    o.x = f2bf(v.x); o.y = f2bf(v.y); o.z = f2bf(v.z); o.w = f2bf(v.w);
    ((ushort4*)xb)[i] = o;
  }
  for (int i = gtid; i < 9*DD*DD; i += CSR_GT){
    int r = i >> 14; int rem = i & 16383; int n = rem >> 7; int k = rem & 127;
    float v = (r < 8) ? w[r*16384 + k*128 + n] : sw[k*128 + n];
    wb[i] = f2bf(v);
  }
  grid.sync();

  // ---- phase 1: count ----
  for (int e = gtid; e < EE; e += CSR_GT){
    int s = ei[e], d = ei[EE + e], t = et[e];
    atomicAdd(&counts[d*RR + t], 1);
    atomicAdd(&counts[s*RR + t], 1);
  }
  grid.sync();

  // ---- phase 2a: per-thread chunk of 4 + block scan ----
  const int base = gtid*4;
  int c0 = (base+0 < SS) ? counts[base+0] : 0;
  int c1 = (base+1 < SS) ? counts[base+1] : 0;
  int c2 = (base+2 < SS) ? counts[base+2] : 0;
  int c3 = (base+3 < SS) ? counts[base+3] : 0;
  int ts = c0+c1+c2+c3;
  sd[tid] = ts; __syncthreads();
  for (int o = 1; o < 256; o <<= 1){
    int t = (tid >= o) ? sd[tid-o] : 0;
    __syncthreads();
    sd[tid] += t;
    __syncthreads();
  }
  int ex = sd[tid] - ts;                 // exclusive within block
  if (tid == 255) blksum[bid] = sd[255];
  grid.sync();

  // ---- phase 2b: block 0 scans the 512 block sums (2 per thread) ----
  if (bid == 0){
    int v0 = blksum[2*tid], v1 = blksum[2*tid+1];
    int t2 = v0 + v1;
    __syncthreads();                     // sd reuse safe: all threads past 2a use
    sd[tid] = t2; __syncthreads();
    for (int o = 1; o < 256; o <<= 1){
      int t = (tid >= o) ? sd[tid-o] : 0;
      __syncthreads();
      sd[tid] += t;
      __syncthreads();
    }
    int ex2 = sd[tid] - t2;
    blksum[2*tid]   = ex2;
    blksum[2*tid+1] = ex2 + v0;
  }
  grid.sync();

  // ---- phase 2c: write offs + cursor ----
  int pref = blksum[bid] + ex;
  if (base+0 < SS){ offs[base+0] = pref; cursor[base+0] = pref; } pref += c0;
  if (base+1 < SS){ offs[base+1] = pref; cursor[base+1] = pref; } pref += c1;
  if (base+2 < SS){ offs[base+2] = pref; cursor[base+2] = pref; } pref += c2;
  if (base+3 < SS){ offs[base+3] = pref; cursor[base+3] = pref; }
  if (gtid == 0) offs[SS] = TE;
  grid.sync();

  // ---- phase 3: scatter ----
  for (int e = gtid; e < EE; e += CSR_GT){
    int s = ei[e], d = ei[EE + e], t = et[e];
    int p = atomicAdd(&cursor[d*RR + t], 1); esrc[p] = s;
    int q = atomicAdd(&cursor[s*RR + t], 1); esrc[q] = d;
  }
}

// ---- fused gather + degree-scale + GEMM (unchanged from R3) ---------------
__global__ __launch_bounds__(256) void k_fused(
    const unsigned short* __restrict__ xb,
    const unsigned short* __restrict__ wb,
    const int* __restrict__ offs,
    const int* __restrict__ esrc,
    float* __restrict__ out)
{
  __shared__ __align__(16) unsigned short Alds[2][32][136]; // +8 pad: 2-way bank alias (free)
  const int tid  = threadIdx.x;
  const int wave = tid >> 6, lane = tid & 63;
  const int l15  = lane & 15, quad = lane >> 4;
  const int g    = quad;          // 16-lane group id within wave
  const int gl   = l15;           // lane within group
  const int gbase = g << 4;       // wave-lane index of group's lane 0
  const int rowbase = blockIdx.x * 32;

  f32x4 C[2][2];
  #pragma unroll
  for (int m = 0; m < 2; ++m){ C[m][0] = (f32x4)(0.f); C[m][1] = (f32x4)(0.f); }

  auto gather = [&](int rr, int b){
    int v = 0;
    if (rr < 8 && lane < 16){
      int gdj = rowbase + wave*8 + (lane >> 1);
      if (gdj < NN) v = offs[gdj*8 + rr + (lane & 1)];
    }
    #pragma unroll
    for (int p = 0; p < 2; ++p){
      int rl8  = 2*g + p;            // row within wave's 8
      int rowl = wave*8 + rl8;       // row within 32-row tile
      int gd   = rowbase + rowl;
      uint4 u = make_uint4(0u,0u,0u,0u);
      if (rr == 8){
        if (gd < NN) u = *(const uint4*)(xb + (size_t)gd*DD + gl*8);
      } else {
        int off = __shfl(v, 2*rl8);
        int end = __shfl(v, 2*rl8 + 1);
        int cnt = (gd < NN) ? (end - off) : 0;
        float a[8] = {0.f,0.f,0.f,0.f,0.f,0.f,0.f,0.f};
        int idxv = 0;
        if (gl < cnt) idxv = esrc[off + gl];     // first up-to-16 srcs, coalesced
        int cm = cnt < 16 ? cnt : 16;
        int e = 0;
        for (; e + 4 <= cm; e += 4){
          int s0 = __shfl(idxv, gbase + e + 0);
          int s1 = __shfl(idxv, gbase + e + 1);
          int s2 = __shfl(idxv, gbase + e + 2);
          int s3 = __shfl(idxv, gbase + e + 3);
          uint4 u0 = *(const uint4*)(xb + (size_t)s0*DD + gl*8);
          uint4 u1 = *(const uint4*)(xb + (size_t)s1*DD + gl*8);
          uint4 u2 = *(const uint4*)(xb + (size_t)s2*DD + gl*8);
          uint4 u3 = *(const uint4*)(xb + (size_t)s3*DD + gl*8);
          acc8(a, u0); acc8(a, u1); acc8(a, u2); acc8(a, u3);
        }
        for (; e < cm; ++e){
          int s0 = __shfl(idxv, gbase + e);
          uint4 u0 = *(const uint4*)(xb + (size_t)s0*DD + gl*8);
          acc8(a, u0);
        }
        for (int e2 = 16; e2 < cnt; ++e2){       // rare Poisson tail (cnt>16)
          int s0 = esrc[off + e2];
          uint4 u0 = *(const uint4*)(xb + (size_t)s0*DD + gl*8);
          acc8(a, u0);
        }
        float sc = (cnt > 0) ? (1.0f / (float)cnt) : 0.f;
        u.x = pack2(a[0]*sc, a[1]*sc);
        u.y = pack2(a[2]*sc, a[3]*sc);
        u.z = pack2(a[4]*sc, a[5]*sc);
        u.w = pack2(a[6]*sc, a[7]*sc);
      }
      *(uint4*)&Alds[b][rowl][gl*8] = u;
    }
  };

  gather(0, 0);
  __syncthreads();

  #pragma unroll 1
  for (int rr = 0; rr < 9; ++rr){
    int b = rr & 1;
    if (rr < 8) gather(rr + 1, b ^ 1);   // overlaps MFMA phase below

    const unsigned short* wr = wb + rr * 16384;
    bf16x8 bfrag[2][4];
    #pragma unroll
    for (int nt = 0; nt < 2; ++nt)
      #pragma unroll
      for (int ks = 0; ks < 4; ++ks)
        bfrag[nt][ks] = *(const bf16x8*)(wr + (wave*32 + nt*16 + l15)*128 + ks*32 + quad*8);

    #pragma unroll
    for (int m = 0; m < 2; ++m){
      #pragma unroll
      for (int ks = 0; ks < 4; ++ks){
        bf16x8 af = *(const bf16x8*)&Alds[b][m*16 + l15][ks*32 + quad*8];
        C[m][0] = __builtin_amdgcn_mfma_f32_16x16x32_bf16(af, bfrag[0][ks], C[m][0], 0, 0, 0);
        C[m][1] = __builtin_amdgcn_mfma_f32_16x16x32_bf16(af, bfrag[1][ks], C[m][1], 0, 0, 0);
      }
    }
    __syncthreads();
  }

  // epilogue: C/D layout col = lane&15, row = quad*4 + reg
  #pragma unroll
  for (int m = 0; m < 2; ++m){
    #pragma unroll
    for (int nt = 0; nt < 2; ++nt){
      #pragma unroll
      for (int i = 0; i < 4; ++i){
        int row = m*16 + quad*4 + i;
        int gd  = rowbase + row;
        int col = wave*32 + nt*16 + l15;
        if (gd < NN) out[gd*DD + col] = C[m][nt][i];
      }
    }
  }
}

// ---- workspace layout (bytes) ---------------------------------------------
// counts   @ 0          : SS*4        = 1,600,000
// offs     @ 1,600,000  : (SS+1)*4    = 1,600,004 (+pad)
// cursor   @ 3,200,016  : SS*4        = 1,600,000
// blksum   @ 4,800,016  : 512*4       = 2,048
// esrc     @ 4,802,064  : TE*4        = 6,400,000
// xb       @ 11,202,064 : NN*DD*2     = 12,800,000
// wb       @ 24,002,064 : 9*DD*DD*2   = 294,912
// total ~ 24.30 MB
extern "C" void kernel_launch(void* const* d_in, const int* in_sizes, int n_in,
                              void* d_out, int out_size, void* d_ws, size_t ws_size,
                              hipStream_t stream){
  const float* x  = (const float*)d_in[0];
  const float* w  = (const float*)d_in[1];
  const float* sw = (const float*)d_in[2];
  const int*   ei = (const int*)d_in[3];
  const int*   et = (const int*)d_in[4];
  float* out = (float*)d_out;
  char* ws = (char*)d_ws;

  if (ws_size < (size_t)24300000) return;

  int* counts = (int*)(ws + 0);
  int* offs   = (int*)(ws + 1600000);
  int* cursor = (int*)(ws + 3200016);
  int* blksum = (int*)(ws + 4800016);
  int* esrc   = (int*)(ws + 4802064);
  unsigned short* xb = (unsigned short*)(ws + 11202064);
  unsigned short* wb = (unsigned short*)(ws + 24002064);

  void* args[12] = { (void*)&x, (void*)&w, (void*)&sw, (void*)&ei, (void*)&et,
                     (void*)&xb, (void*)&wb, (void*)&counts, (void*)&offs,
                     (void*)&cursor, (void*)&esrc, (void*)&blksum };
  hipLaunchCooperativeKernel((void*)k_csr, dim3(CSR_BLOCKS), dim3(256),
                             args, 0, stream);
  k_fused<<<(NN + 31)/32, 256, 0, stream>>>(xb, wb, offs, esrc, out);
}

// Round 5
// 259.390 us; speedup vs baseline: 2.7173x; 2.7173x over previous
//
#include <hip/hip_runtime.h>

#define NN 50000
#define EE 800000
#define RR 8
#define DD 128
#define SS (NN*RR)        // 400000 segments
#define TE (2*EE)         // 1600000 directed edges
#define NB 782            // dst buckets of 64 nodes
#define NBLK 391          // partition blocks, 4096 directed edges each
#define NS (NB*NBLK)      // 305762 scan elements

typedef __attribute__((ext_vector_type(8))) short bf16x8;
typedef __attribute__((ext_vector_type(4))) float f32x4;

__device__ __forceinline__ unsigned short f2bf(float f){
  unsigned int u = __float_as_uint(f);
  u += 0x7fffu + ((u >> 16) & 1u);   // round-to-nearest-even
  return (unsigned short)(u >> 16);
}
__device__ __forceinline__ float bf_lo(unsigned int w){ return __uint_as_float(w << 16); }
__device__ __forceinline__ float bf_hi(unsigned int w){ return __uint_as_float(w & 0xffff0000u); }

__device__ __forceinline__ void acc8(float* a, uint4 u){
  a[0] += bf_lo(u.x); a[1] += bf_hi(u.x);
  a[2] += bf_lo(u.y); a[3] += bf_hi(u.y);
  a[4] += bf_lo(u.z); a[5] += bf_hi(u.z);
  a[6] += bf_lo(u.w); a[7] += bf_hi(u.w);
}
__device__ __forceinline__ unsigned int pack2(float a, float b){
  return ((unsigned int)f2bf(b) << 16) | (unsigned int)f2bf(a);
}

// directed edge j in [0,TE): j<EE forward (s->d), else reversed
__device__ __forceinline__ void dir_edge(const int* ei, const int* et, int j,
                                         int& s, int& d, int& t){
  if (j < EE){ s = ei[j]; d = ei[EE + j]; t = et[j]; }
  else { int jj = j - EE; s = ei[EE + jj]; d = ei[jj]; t = et[jj]; }
}

// ---- partition phase A1: per-(bucket,block) histogram ---------------------
__global__ __launch_bounds__(256) void k_hist(const int* __restrict__ ei,
                                              const int* __restrict__ et,
                                              int* __restrict__ hist){
  __shared__ int h[NB];
  int tid = threadIdx.x, bid = blockIdx.x;
  for (int i = tid; i < NB; i += 256) h[i] = 0;
  __syncthreads();
  int j0 = bid*4096;
  for (int k = tid; k < 4096; k += 256){
    int j = j0 + k;
    if (j < TE){
      int s, d, t; dir_edge(ei, et, j, s, d, t);
      atomicAdd(&h[d >> 6], 1);           // LDS atomic
    }
  }
  __syncthreads();
  for (int i = tid; i < NB; i += 256) hist[i*NBLK + bid] = h[i];
}

// ---- scan over NS elements (in-place exclusive), 3 kernels ----------------
__global__ __launch_bounds__(256) void k_scan1(int* __restrict__ hist,
                                               int* __restrict__ blksum){
  __shared__ int sd[256];
  int b = blockIdx.x, tid = threadIdx.x;
  int base = b*1024 + tid*4;
  int v0 = (base+0 < NS) ? hist[base+0] : 0;
  int v1 = (base+1 < NS) ? hist[base+1] : 0;
  int v2 = (base+2 < NS) ? hist[base+2] : 0;
  int v3 = (base+3 < NS) ? hist[base+3] : 0;
  int ts = v0+v1+v2+v3;
  sd[tid] = ts; __syncthreads();
  for (int o = 1; o < 256; o <<= 1){
    int t = (tid >= o) ? sd[tid-o] : 0;
    __syncthreads();
    sd[tid] += t;
    __syncthreads();
  }
  int ex = sd[tid] - ts;
  if (base+0 < NS) hist[base+0] = ex; ex += v0;
  if (base+1 < NS) hist[base+1] = ex; ex += v1;
  if (base+2 < NS) hist[base+2] = ex; ex += v2;
  if (base+3 < NS) hist[base+3] = ex;
  if (tid == 255) blksum[b] = sd[255];
}

__global__ __launch_bounds__(512) void k_scan2(int* __restrict__ blksum, int nb){
  __shared__ int sd[512];
  int tid = threadIdx.x;
  int v = (tid < nb) ? blksum[tid] : 0;
  sd[tid] = v; __syncthreads();
  for (int o = 1; o < 512; o <<= 1){
    int t = (tid >= o) ? sd[tid-o] : 0;
    __syncthreads();
    sd[tid] += t;
    __syncthreads();
  }
  if (tid < nb) blksum[tid] = sd[tid] - v;   // exclusive
}

__global__ __launch_bounds__(256) void k_scan3(int* __restrict__ hist,
                                               const int* __restrict__ blksum){
  int i = blockIdx.x*blockDim.x + threadIdx.x;
  if (i < NS) hist[i] += blksum[i >> 10];
}

// ---- partition phase A3: place packed edges into bucket slices ------------
// packed: src (17b) | dstlo (6b @17) | rel (3b @23)
__global__ __launch_bounds__(256) void k_part(const int* __restrict__ ei,
                                              const int* __restrict__ et,
                                              const int* __restrict__ S,
                                              unsigned int* __restrict__ P){
  __shared__ int cur[NB];
  int tid = threadIdx.x, bid = blockIdx.x;
  for (int i = tid; i < NB; i += 256) cur[i] = S[i*NBLK + bid];
  __syncthreads();
  int j0 = bid*4096;
  for (int k = tid; k < 4096; k += 256){
    int j = j0 + k;
    if (j < TE){
      int s, d, t; dir_edge(ei, et, j, s, d, t);
      int b = d >> 6;
      int p = atomicAdd(&cur[b], 1);       // LDS atomic rank
      P[p] = (unsigned int)s | ((unsigned int)(d & 63) << 17)
           | ((unsigned int)t << 23);
    }
  }
}

// ---- phase B: per-bucket counting sort -> offs + esrc ---------------------
__global__ __launch_bounds__(256) void k_build(const unsigned int* __restrict__ P,
                                               const int* __restrict__ S,
                                               int* __restrict__ esrc,
                                               int* __restrict__ offs){
  __shared__ int h[512], cu[512], sd[256];
  int tid = threadIdx.x, b = blockIdx.x;
  int pstart = S[b*NBLK];
  int pend   = (b+1 < NB) ? S[(b+1)*NBLK] : TE;
  int ne = pend - pstart;
  h[2*tid] = 0; h[2*tid+1] = 0;
  __syncthreads();
  for (int k = tid; k < ne; k += 256){
    unsigned int u = P[pstart + k];
    int lseg = (int)(((u >> 17) & 63u)*8u + (u >> 23));
    atomicAdd(&h[lseg], 1);                // LDS atomic
  }
  __syncthreads();
  // exclusive scan of 512 bins with 256 threads
  int v0 = h[2*tid], v1 = h[2*tid+1];
  int ts = v0 + v1;
  sd[tid] = ts; __syncthreads();
  for (int o = 1; o < 256; o <<= 1){
    int t = (tid >= o) ? sd[tid-o] : 0;
    __syncthreads();
    sd[tid] += t;
    __syncthreads();
  }
  int ex = sd[tid] - ts;
  cu[2*tid]   = pstart + ex;
  cu[2*tid+1] = pstart + ex + v0;
  int seg0 = b*512;
  if (seg0 + 2*tid     < SS) offs[seg0 + 2*tid]     = cu[2*tid];
  if (seg0 + 2*tid + 1 < SS) offs[seg0 + 2*tid + 1] = cu[2*tid+1];
  if (b == NB-1 && tid == 0) offs[SS] = TE;
  __syncthreads();
  for (int k = tid; k < ne; k += 256){
    unsigned int u = P[pstart + k];
    int lseg = (int)(((u >> 17) & 63u)*8u + (u >> 23));
    int r = atomicAdd(&cu[lseg], 1);       // LDS atomic
    esrc[r] = (int)(u & 0x1ffffu);
  }
}

// ---- merged conversions: x->bf16, W/self_W -> bf16 transposed -------------
__global__ __launch_bounds__(256) void k_conv(const float* __restrict__ x,
                                              const float* __restrict__ w,
                                              const float* __restrict__ sw,
                                              unsigned short* __restrict__ xb,
                                              unsigned short* __restrict__ wb){
  int i = blockIdx.x*blockDim.x + threadIdx.x;
  const int M1 = NN*DD/4;            // 1,600,000 float4 groups
  if (i < M1){
    float4 v = ((const float4*)x)[i];
    ushort4 o;
    o.x = f2bf(v.x); o.y = f2bf(v.y); o.z = f2bf(v.z); o.w = f2bf(v.w);
    ((ushort4*)xb)[i] = o;
  } else {
    int j = i - M1;
    if (j < 9*DD*DD){
      int r = j >> 14; int rem = j & 16383; int n = rem >> 7; int k = rem & 127;
      float v = (r < 8) ? w[r*16384 + k*128 + n] : sw[k*128 + n];
      wb[j] = f2bf(v);
    }
  }
}

// ---- fused gather + degree-scale + GEMM (unchanged from R3) ---------------
__global__ __launch_bounds__(256) void k_fused(
    const unsigned short* __restrict__ xb,
    const unsigned short* __restrict__ wb,
    const int* __restrict__ offs,
    const int* __restrict__ esrc,
    float* __restrict__ out)
{
  __shared__ __align__(16) unsigned short Alds[2][32][136]; // +8 pad: 2-way bank alias (free)
  const int tid  = threadIdx.x;
  const int wave = tid >> 6, lane = tid & 63;
  const int l15  = lane & 15, quad = lane >> 4;
  const int g    = quad;
  const int gl   = l15;
  const int gbase = g << 4;
  const int rowbase = blockIdx.x * 32;

  f32x4 C[2][2];
  #pragma unroll
  for (int m = 0; m < 2; ++m){ C[m][0] = (f32x4)(0.f); C[m][1] = (f32x4)(0.f); }

  auto gather = [&](int rr, int b){
    int v = 0;
    if (rr < 8 && lane < 16){
      int gdj = rowbase + wave*8 + (lane >> 1);
      if (gdj < NN) v = offs[gdj*8 + rr + (lane & 1)];
    }
    #pragma unroll
    for (int p = 0; p < 2; ++p){
      int rl8  = 2*g + p;
      int rowl = wave*8 + rl8;
      int gd   = rowbase + rowl;
      uint4 u = make_uint4(0u,0u,0u,0u);
      if (rr == 8){
        if (gd < NN) u = *(const uint4*)(xb + (size_t)gd*DD + gl*8);
      } else {
        int off = __shfl(v, 2*rl8);
        int end = __shfl(v, 2*rl8 + 1);
        int cnt = (gd < NN) ? (end - off) : 0;
        float a[8] = {0.f,0.f,0.f,0.f,0.f,0.f,0.f,0.f};
        int idxv = 0;
        if (gl < cnt) idxv = esrc[off + gl];
        int cm = cnt < 16 ? cnt : 16;
        int e = 0;
        for (; e + 4 <= cm; e += 4){
          int s0 = __shfl(idxv, gbase + e + 0);
          int s1 = __shfl(idxv, gbase + e + 1);
          int s2 = __shfl(idxv, gbase + e + 2);
          int s3 = __shfl(idxv, gbase + e + 3);
          uint4 u0 = *(const uint4*)(xb + (size_t)s0*DD + gl*8);
          uint4 u1 = *(const uint4*)(xb + (size_t)s1*DD + gl*8);
          uint4 u2 = *(const uint4*)(xb + (size_t)s2*DD + gl*8);
          uint4 u3 = *(const uint4*)(xb + (size_t)s3*DD + gl*8);
          acc8(a, u0); acc8(a, u1); acc8(a, u2); acc8(a, u3);
        }
        for (; e < cm; ++e){
          int s0 = __shfl(idxv, gbase + e);
          uint4 u0 = *(const uint4*)(xb + (size_t)s0*DD + gl*8);
          acc8(a, u0);
        }
        for (int e2 = 16; e2 < cnt; ++e2){
          int s0 = esrc[off + e2];
          uint4 u0 = *(const uint4*)(xb + (size_t)s0*DD + gl*8);
          acc8(a, u0);
        }
        float sc = (cnt > 0) ? (1.0f / (float)cnt) : 0.f;
        u.x = pack2(a[0]*sc, a[1]*sc);
        u.y = pack2(a[2]*sc, a[3]*sc);
        u.z = pack2(a[4]*sc, a[5]*sc);
        u.w = pack2(a[6]*sc, a[7]*sc);
      }
      *(uint4*)&Alds[b][rowl][gl*8] = u;
    }
  };

  gather(0, 0);
  __syncthreads();

  #pragma unroll 1
  for (int rr = 0; rr < 9; ++rr){
    int b = rr & 1;
    if (rr < 8) gather(rr + 1, b ^ 1);

    const unsigned short* wr = wb + rr * 16384;
    bf16x8 bfrag[2][4];
    #pragma unroll
    for (int nt = 0; nt < 2; ++nt)
      #pragma unroll
      for (int ks = 0; ks < 4; ++ks)
        bfrag[nt][ks] = *(const bf16x8*)(wr + (wave*32 + nt*16 + l15)*128 + ks*32 + quad*8);

    #pragma unroll
    for (int m = 0; m < 2; ++m){
      #pragma unroll
      for (int ks = 0; ks < 4; ++ks){
        bf16x8 af = *(const bf16x8*)&Alds[b][m*16 + l15][ks*32 + quad*8];
        C[m][0] = __builtin_amdgcn_mfma_f32_16x16x32_bf16(af, bfrag[0][ks], C[m][0], 0, 0, 0);
        C[m][1] = __builtin_amdgcn_mfma_f32_16x16x32_bf16(af, bfrag[1][ks], C[m][1], 0, 0, 0);
      }
    }
    __syncthreads();
  }

  #pragma unroll
  for (int m = 0; m < 2; ++m){
    #pragma unroll
    for (int nt = 0; nt < 2; ++nt){
      #pragma unroll
      for (int i = 0; i < 4; ++i){
        int row = m*16 + quad*4 + i;
        int gd  = rowbase + row;
        int col = wave*32 + nt*16 + l15;
        if (gd < NN) out[gd*DD + col] = C[m][nt][i];
      }
    }
  }
}

// ---- workspace layout (bytes) ---------------------------------------------
// xb     @ 0          : NN*DD*2 = 12,800,000
//   (aliased during partition: hist @ 0 (1,223,168), blksum @ 1,223,168
//    (2,048), P @ 1,225,216 (6,400,000) — all dead before k_conv writes xb)
// esrc   @ 12,800,000 : TE*4    = 6,400,000
// offs   @ 19,200,000 : (SS+1)*4 -> 1,600,016
// wb     @ 20,800,016 : 9*DD*DD*2 = 294,912
// total 21,094,928
extern "C" void kernel_launch(void* const* d_in, const int* in_sizes, int n_in,
                              void* d_out, int out_size, void* d_ws, size_t ws_size,
                              hipStream_t stream){
  const float* x  = (const float*)d_in[0];
  const float* w  = (const float*)d_in[1];
  const float* sw = (const float*)d_in[2];
  const int*   ei = (const int*)d_in[3];
  const int*   et = (const int*)d_in[4];
  float* out = (float*)d_out;
  char* ws = (char*)d_ws;

  if (ws_size < (size_t)21100000) return;

  unsigned short* xb = (unsigned short*)(ws + 0);
  int*          hist = (int*)(ws + 0);               // alias (dead before xb)
  int*        blksum = (int*)(ws + 1223168);         // alias
  unsigned int*    P = (unsigned int*)(ws + 1225216);// alias
  int*          esrc = (int*)(ws + 12800000);
  int*          offs = (int*)(ws + 19200000);
  unsigned short* wb = (unsigned short*)(ws + 20800016);

  k_hist <<<NBLK, 256, 0, stream>>>(ei, et, hist);
  k_scan1<<<(NS + 1023)/1024, 256, 0, stream>>>(hist, blksum);   // 299 blocks
  k_scan2<<<1, 512, 0, stream>>>(blksum, (NS + 1023)/1024);
  k_scan3<<<(NS + 255)/256, 256, 0, stream>>>(hist, blksum);
  k_part <<<NBLK, 256, 0, stream>>>(ei, et, hist, P);
  k_build<<<NB, 256, 0, stream>>>(P, hist, esrc, offs);
  k_conv <<<(NN*DD/4 + 9*DD*DD + 255)/256, 256, 0, stream>>>(x, w, sw, xb, wb);
  k_fused<<<(NN + 31)/32, 256, 0, stream>>>(xb, wb, offs, esrc, out);
}